// Round 11
// baseline (199.931 us; speedup 1.0000x reference)
//
#include <hip/hip_runtime.h>
#include <math.h>

// Problem constants
#define BATCH 8
#define WAY 5
#define NQ 75
#define NSAMP 80
#define NP 9
#define CCH 640
#define KLEN 192
#define NIMG (BATCH*NSAMP*NP)   // 5760
#define AS 200                  // LDS row stride (bf16 elems) for A tiles
#define NTILES 20               // 640/32 n-tiles
#define NKS 12                  // 192/16 k-steps
#define NFRAG (NTILES*NKS*64)   // 15360 lane-fragments per plane
#define QKS 20                  // 640/32 k-steps for sim MFMA
#define NSET 3                  // 48 support rows = 3 sets of 16

typedef short bf16x8 __attribute__((ext_vector_type(8)));
typedef float f32x16 __attribute__((ext_vector_type(16)));
typedef float f32x4  __attribute__((ext_vector_type(4)));

__device__ __forceinline__ void split_bf16(float x, short& hi, short& lo) {
    unsigned xb = __float_as_uint(x);
    hi = (short)(xb >> 16);
    float hf = __uint_as_float(xb & 0xFFFF0000u);
    float r = x - hf;
    lo = (short)(__float_as_uint(r) >> 16);
}

// ---------------------------------------------------------------------------
// Prep: split conv_w (640x192 fp32) into packed bf16 hi/lo B-fragments.
// Fragment f = nt*12+ks, lane l, elem j: w[nt*32+(l&31)][ks*16+(l>>5)*8+j].
__global__ __launch_bounds__(256) void prep_w_pack(
    const float* __restrict__ w, short* __restrict__ w_hi, short* __restrict__ w_lo)
{
    int f = blockIdx.x * 256 + threadIdx.x;   // float4 index, < 30720
    if (f < CCH * KLEN / 4) {
        int c  = f / 48;
        int kq = f - c * 48;                  // k = kq*4
        int nt = c >> 5;
        int ks = kq >> 2;
        int lane = (c & 31) | (((kq >> 1) & 1) << 5);
        int j = (kq & 1) << 2;
        float4 v = ((const float4*)w)[f];
        short h0, h1, h2, h3, l0, l1, l2, l3;
        split_bf16(v.x, h0, l0);
        split_bf16(v.y, h1, l1);
        split_bf16(v.z, h2, l2);
        split_bf16(v.w, h3, l3);
        size_t dst = ((size_t)(nt * NKS + ks) * 64 + lane) * 8 + j;
        *(short4*)(w_hi + dst) = make_short4(h0, h1, h2, h3);
        *(short4*)(w_lo + dst) = make_short4(l0, l1, l2, l3);
    }
}

// ---------------------------------------------------------------------------
// Kernel 1 v5: 256-thread blocks, M=64 (4 images), target 3 blocks/CU.
// Changes vs v4: (a) B-prefetch ring distance 3 (covers L2 latency ~250 cyc
// vs ~100 covered before); (b) epilogue scratch (pooled/ssq/inv) OVERLAYS the
// dead A-tile LDS -> 51.2 KB/block so 3 blocks fit in 160 KB, enabling
// cross-block overlap of staging/epilogue with K-loops.
__global__ __launch_bounds__(256, 2) void conv_mfma(
    const float* __restrict__ x,      // [NIMG,3,32,32]
    const short* __restrict__ w_hi,   // packed B-fragments
    const short* __restrict__ w_lo,
    short* __restrict__ fh,           // [NIMG][640] bf16 hi
    short* __restrict__ fl)           // [NIMG][640] bf16 lo
{
    __shared__ short Ah[64 * AS];             // 25.6 KB  (epilogue: pooled_s)
    __shared__ short Al[64 * AS];             // 25.6 KB  (epilogue: ssq/inv/rn)
    // Overlays (valid only after the post-K-loop barrier; A is dead then):
    float* pooled_s = (float*)Ah;             // 4*640 floats = 10.2 KB
    float* ssq_part = (float*)Al;             // 4*64 floats  = 1 KB
    float* inv_s    = (float*)Al + 256;       // 64 floats
    float* rn_part  = (float*)Al + 320;       // 4 floats
    float* invc_s   = (float*)Al + 324;       // 4 floats

    const int t = threadIdx.x;
    const int blk = blockIdx.x;

    // ---- load 4 images, rearrange to A[row=img*16+pos][k], split hi/lo
    {
        const float4* xp = (const float4*)(x + (size_t)blk * 4 * 3072);
#pragma unroll
        for (int i = 0; i < 12; i++) {
            int f = t + i * 256;              // 0..3071 float4s
            int img = f / 768;
            int rem = f - img * 768;
            int ci = rem >> 8;
            int rem2 = rem & 255;
            int h = rem2 >> 3;
            int w4 = (rem2 & 7) << 2;
            int s = ((h >> 3) << 2) + (w4 >> 3);
            int k0 = (ci << 6) + ((h & 7) << 3) + (w4 & 7);
            int row = (img << 4) + s;
            float4 v = xp[f];
            short h0, h1, h2, h3, l0, l1, l2, l3;
            split_bf16(v.x, h0, l0);
            split_bf16(v.y, h1, l1);
            split_bf16(v.z, h2, l2);
            split_bf16(v.w, h3, l3);
            *(short4*)&Ah[row * AS + k0] = make_short4(h0, h1, h2, h3);
            *(short4*)&Al[row * AS + k0] = make_short4(l0, l1, l2, l3);
        }
    }
    __syncthreads();

    const int wv = t >> 6;       // wave 0..3
    const int l  = t & 63;
    const int ln = l & 31;       // MFMA col lane
    const int hh = l >> 5;       // k-half

    f32x16 acc[10];              // acc[i*2 + mt]
#pragma unroll
    for (int j = 0; j < 10; j++)
#pragma unroll
        for (int r = 0; r < 16; r++) acc[j][r] = 0.f;

    const bf16x8* BH = (const bf16x8*)w_hi + (size_t)(wv * 5) * (NKS * 64) + l;
    const bf16x8* BL = (const bf16x8*)w_lo + (size_t)(wv * 5) * (NKS * 64) + l;
    const int abase = ln * AS + hh * 8;

    // K-loop: flat p = ks*5 + i (ks-outer so A is read once per ks).
    // B offset for (i,ks): (i*NKS + ks)*64. Distance-3 register ring.
    {
        bf16x8 rh[3], rl[3];
#pragma unroll
        for (int q = 0; q < 3; q++) {
            const int off = ((q % 5) * NKS + q / 5) * 64;
            rh[q] = BH[off];
            rl[q] = BL[off];
        }
        bf16x8 aH0, aL0, aH1, aL1;
#pragma unroll
        for (int p = 0; p < 60; p++) {
            const int s = p % 3;
            const int ks = p / 5;
            const int i  = p % 5;
            bf16x8 bh = rh[s], bl = rl[s];
            if (p + 3 < 60) {
                const int pn = p + 3;
                const int off = ((pn % 5) * NKS + pn / 5) * 64;
                rh[s] = BH[off];
                rl[s] = BL[off];
            }
            if (i == 0) {
                aH0 = *(const bf16x8*)&Ah[abase + ks * 16];
                aL0 = *(const bf16x8*)&Al[abase + ks * 16];
                aH1 = *(const bf16x8*)&Ah[abase + 32 * AS + ks * 16];
                aL1 = *(const bf16x8*)&Al[abase + 32 * AS + ks * 16];
            }
            acc[i * 2 + 0] = __builtin_amdgcn_mfma_f32_32x32x16_bf16(aH0, bh, acc[i * 2 + 0], 0, 0, 0);
            acc[i * 2 + 0] = __builtin_amdgcn_mfma_f32_32x32x16_bf16(aL0, bh, acc[i * 2 + 0], 0, 0, 0);
            acc[i * 2 + 0] = __builtin_amdgcn_mfma_f32_32x32x16_bf16(aH0, bl, acc[i * 2 + 0], 0, 0, 0);
            acc[i * 2 + 1] = __builtin_amdgcn_mfma_f32_32x32x16_bf16(aH1, bh, acc[i * 2 + 1], 0, 0, 0);
            acc[i * 2 + 1] = __builtin_amdgcn_mfma_f32_32x32x16_bf16(aL1, bh, acc[i * 2 + 1], 0, 0, 0);
            acc[i * 2 + 1] = __builtin_amdgcn_mfma_f32_32x32x16_bf16(aH1, bl, acc[i * 2 + 1], 0, 0, 0);
        }
    }

    __syncthreads();   // A-tiles dead from here: overlays become valid

    // ---- ssq per row. C/D layout (32x32): col=ln, rl=(r&3)+8*(r>>2)+4*hh.
    {
        float rs0[16], rs1[16];
#pragma unroll
        for (int r = 0; r < 16; r++) { rs0[r] = 0.f; rs1[r] = 0.f; }
#pragma unroll
        for (int i = 0; i < 5; i++) {
#pragma unroll
            for (int r = 0; r < 16; r++) {
                rs0[r] += acc[i * 2 + 0][r] * acc[i * 2 + 0][r];
                rs1[r] += acc[i * 2 + 1][r] * acc[i * 2 + 1][r];
            }
        }
#pragma unroll
        for (int r = 0; r < 16; r++) {
            float v0 = rs0[r], v1 = rs1[r];
            v0 += __shfl_xor(v0, 1);  v1 += __shfl_xor(v1, 1);
            v0 += __shfl_xor(v0, 2);  v1 += __shfl_xor(v1, 2);
            v0 += __shfl_xor(v0, 4);  v1 += __shfl_xor(v1, 4);
            v0 += __shfl_xor(v0, 8);  v1 += __shfl_xor(v1, 8);
            v0 += __shfl_xor(v0, 16); v1 += __shfl_xor(v1, 16);
            if (ln == 0) {
                int rl = (r & 3) + ((r >> 2) << 3) + (hh << 2);
                ssq_part[wv * 64 + rl] = v0;
                ssq_part[wv * 64 + 32 + rl] = v1;
            }
        }
    }
    __syncthreads();
    if (t < 64) {
        float s = ssq_part[t] + ssq_part[64 + t] + ssq_part[128 + t] + ssq_part[192 + t];
        inv_s[t] = 1.f / fmaxf(sqrtf(s), 1e-12f);
    }
    __syncthreads();

    float iv0[16], iv1[16];
#pragma unroll
    for (int r = 0; r < 16; r++) {
        int rl = (r & 3) + ((r >> 2) << 3) + (hh << 2);
        iv0[r] = inv_s[rl];
        iv1[r] = inv_s[32 + rl];
    }

    // ---- pooled[img][c] = sum_pos inv[row]*C[row][c] (into Ah overlay)
#pragma unroll
    for (int i = 0; i < 5; i++) {
        const int c = (wv * 5 + i) * 32 + ln;
#pragma unroll
        for (int mt = 0; mt < 2; mt++) {
            float p0 = 0.f, p1 = 0.f;
#pragma unroll
            for (int r = 0; r < 16; r++) {
                float pv = acc[i * 2 + mt][r] * ((mt == 0) ? iv0[r] : iv1[r]);
                if (r < 8) p0 += pv; else p1 += pv;
            }
            p0 += __shfl_xor(p0, 32);
            p1 += __shfl_xor(p1, 32);
            if (hh == 0) {
                pooled_s[(mt * 2 + 0) * CCH + c] = p0;
                pooled_s[(mt * 2 + 1) * CCH + c] = p1;
            }
        }
    }
    __syncthreads();

    // ---- per-image row L2-norm (wave wv handles image wv)
    {
        float s = 0.f;
#pragma unroll
        for (int j = 0; j < 10; j++) {
            float pv = pooled_s[wv * CCH + l + 64 * j];
            s += pv * pv;
        }
        s += __shfl_xor(s, 1);
        s += __shfl_xor(s, 2);
        s += __shfl_xor(s, 4);
        s += __shfl_xor(s, 8);
        s += __shfl_xor(s, 16);
        s += __shfl_xor(s, 32);
        if (l == 0) rn_part[wv] = s;
    }
    __syncthreads();
    if (t < 4)
        invc_s[t] = 1.f / fmaxf(sqrtf(rn_part[t]), 1e-12f);
    __syncthreads();
#pragma unroll
    for (int e0 = 0; e0 < 10; e0++) {
        int e = t + e0 * 256;                 // 0..2559
        int im = e / CCH;
        int c2 = e - im * CCH;
        float v = pooled_s[e] * invc_s[im];
        short vh, vl;
        split_bf16(v, vh, vl);
        size_t o = ((size_t)blk * 4 + im) * CCH + c2;
        fh[o] = vh;
        fl[o] = vl;
    }
}

// ---------------------------------------------------------------------------
// pack_s: build support-row MFMA A-fragments from fh/fl.
__global__ __launch_bounds__(256) void pack_s(
    const short* __restrict__ fh, const short* __restrict__ fl,
    short* __restrict__ sf_h, short* __restrict__ sf_l)
{
    int e = blockIdx.x * 256 + threadIdx.x;       // < 8*3*20*64 = 30720
    if (e >= BATCH * NSET * QKS * 64) return;
    int l = e & 63;
    int rest = e >> 6;
    int ks = rest % QKS;
    int rest2 = rest / QKS;
    int set = rest2 % NSET;
    int b = rest2 / NSET;
    int row48 = set * 16 + (l & 15);
    bf16x8 vh = {0,0,0,0,0,0,0,0}, vl = vh;
    if (row48 < WAY * NP) {
        int m = (row48 * 57) >> 9;                // /9
        int h = row48 - 9 * m;
        size_t src = ((size_t)(b * NSAMP + m) * NP + h) * CCH + ks * 32 + ((l >> 4) << 3);
        vh = *(const bf16x8*)&fh[src];
        vl = *(const bf16x8*)&fl[src];
    }
    *(bf16x8*)&sf_h[(size_t)e * 8] = vh;
    *(bf16x8*)&sf_l[(size_t)e * 8] = vl;
}

// ---------------------------------------------------------------------------
// Kernel 2: per (b,n). A (supports) from packed fragments (coalesced),
// B (query) staged in LDS; 3 MFMA waves; 5 parallel greedy waves.
__global__ __launch_bounds__(320) void sim_mfma(
    const short* __restrict__ fh, const short* __restrict__ fl,
    const short* __restrict__ sf_h, const short* __restrict__ sf_l,
    float* __restrict__ out)                    // [8][75][5]
{
    __shared__ short qb_h[QKS * 64 * 8];        // 20.5 KB B-fragments (hi)
    __shared__ short qb_l[QKS * 64 * 8];        // 20.5 KB (lo)
    __shared__ float sims_s[WAY][84];

    const int n = blockIdx.x;
    const int b = blockIdx.y;
    const int t = threadIdx.x;

    // Stage Q B-fragments: lane l of frag ks holds Q_col(l&15)[ks*32+(l>>4)*8+j]
    for (int e = t; e < QKS * 64; e += 320) {
        int ks = e >> 6;
        int l2 = e & 63;
        int col = l2 & 15;
        int kb = ks * 32 + ((l2 >> 4) << 3);
        if (col < NP) {
            size_t qr = ((size_t)(b * NSAMP + WAY + n) * NP + col) * CCH + kb;
            *(bf16x8*)&qb_h[e * 8] = *(const bf16x8*)&fh[qr];
            *(bf16x8*)&qb_l[e * 8] = *(const bf16x8*)&fl[qr];
        } else {
            bf16x8 z = {0,0,0,0,0,0,0,0};
            *(bf16x8*)&qb_h[e * 8] = z;
            *(bf16x8*)&qb_l[e * 8] = z;
        }
    }
    __syncthreads();

    const int wv = t >> 6;
    const int l = t & 63;

    if (wv < NSET) {
        const bf16x8* AH = (const bf16x8*)sf_h + (size_t)((b * NSET + wv) * QKS) * 64 + l;
        const bf16x8* AL = (const bf16x8*)sf_l + (size_t)((b * NSET + wv) * QKS) * 64 + l;
        f32x4 acc = {0.f, 0.f, 0.f, 0.f};
#pragma unroll
        for (int ks = 0; ks < QKS; ks++) {
            bf16x8 ah = AH[ks * 64];
            bf16x8 al = AL[ks * 64];
            bf16x8 bh = *(const bf16x8*)&qb_h[(ks * 64 + l) * 8];
            bf16x8 bl = *(const bf16x8*)&qb_l[(ks * 64 + l) * 8];
            acc = __builtin_amdgcn_mfma_f32_16x16x32_bf16(ah, bh, acc, 0, 0, 0);
            acc = __builtin_amdgcn_mfma_f32_16x16x32_bf16(al, bh, acc, 0, 0, 0);
            acc = __builtin_amdgcn_mfma_f32_16x16x32_bf16(ah, bl, acc, 0, 0, 0);
        }
        // C/D: col = l&15, row = (l>>4)*4 + r
        int col = l & 15;
#pragma unroll
        for (int r = 0; r < 4; r++) {
            int sidx = wv * 16 + (l >> 4) * 4 + r;
            if (sidx < WAY * NP && col < NP) {
                int mm = (sidx * 57) >> 9;
                int hh2 = sidx - 9 * mm;
                sims_s[mm][hh2 * NP + col] = acc[r];
            }
        }
    }
    __syncthreads();

    // 5 waves, wave wv runs greedy for m = wv.
    {
        float v0 = sims_s[wv][l];
        float v1 = (l < 17) ? sims_s[wv][l + 64] : -3.0e38f;
        int d0r = l / NP, d0c = l - d0r * NP;
        int d1 = l + 64;
        int d1r = d1 / NP, d1c = d1 - d1r * NP;
        unsigned rm = 0x1FF, cm = 0x1FF;
        float total = 0.f, beta = 1.f;
        for (int it = 0; it < NP; it++) {
            float c0 = (((rm >> d0r) & 1u) && ((cm >> d0c) & 1u)) ? v0 : -3.0e38f;
            int i0 = l;
            float c1 = (l < 17 && ((rm >> d1r) & 1u) && ((cm >> d1c) & 1u)) ? v1 : -3.0e38f;
            if (c1 > c0) { c0 = c1; i0 = d1; }
#pragma unroll
            for (int off = 32; off >= 1; off >>= 1) {
                float ov = __shfl_xor(c0, off);
                int oi = __shfl_xor(i0, off);
                if (ov > c0 || (ov == c0 && oi < i0)) { c0 = ov; i0 = oi; }
            }
            total += fmaxf(c0, 0.f) * beta;
            beta *= 0.5f;
            int br = i0 / NP;
            int bc = i0 - br * NP;
            rm &= ~(1u << br);
            cm &= ~(1u << bc);
        }
        if (l == 0) out[((size_t)b * NQ + n) * WAY + wv] = total;
    }
}

extern "C" void kernel_launch(void* const* d_in, const int* in_sizes, int n_in,
                              void* d_out, int out_size, void* d_ws, size_t ws_size,
                              hipStream_t stream) {
    const float* data = (const float*)d_in[0];
    const float* conv_w = (const float*)d_in[1];

    short* fh   = (short*)d_ws;                      // 7,372,800 B
    short* fl   = fh + (size_t)NIMG * CCH;           // 7,372,800 B
    short* w_hi = fl + (size_t)NIMG * CCH;           // 245,760 B
    short* w_lo = w_hi + (size_t)NFRAG * 8;          // 245,760 B
    short* sf_h = w_hi;                              // overlays w (dead after conv)
    short* sf_l = sf_h + (size_t)BATCH * NSET * QKS * 64 * 8;  // 491,520 B each

    prep_w_pack<<<(CCH * KLEN / 4 + 255) / 256, 256, 0, stream>>>(conv_w, w_hi, w_lo);
    conv_mfma<<<NIMG / 4, 256, 0, stream>>>(data, w_hi, w_lo, fh, fl);
    pack_s<<<(BATCH * NSET * QKS * 64 + 255) / 256, 256, 0, stream>>>(fh, fl, sf_h, sf_l);
    dim3 grid(NQ, BATCH);
    sim_mfma<<<grid, 320, 0, stream>>>(fh, fl, sf_h, sf_l, (float*)d_out);
}